// Round 14
// baseline (79.213 us; speedup 1.0000x reference)
//
#include <hip/hip_runtime.h>
#include <math.h>

#define BLOCK 512
#define LOG2_10 3.3219280948873623f
#define PI_F 3.14159265358979f
#define INV2PI 0.15915494309189535f
#define PW_SCALE 256.0f   // lifts Pw out of f16-subnormal range; cancels in out = num/F1

// LDS row strides in f16 elements
#define SP 128   // phiT / B3T rows; granules 0..11 used (K=96)
#define SA 128   // A2 rows
#define FT 56    // full-eval threshold: cells with max(ii,jj) < FT use the exact path

typedef _Float16 half8 __attribute__((ext_vector_type(8)));
typedef _Float16 half2v __attribute__((ext_vector_type(2)));
typedef float f32x4 __attribute__((ext_vector_type(4)));
typedef float v2f  __attribute__((ext_vector_type(2)));
typedef int   i32x4 __attribute__((ext_vector_type(4)));

__device__ __forceinline__ v2f v2(float a, float b) { v2f r; r.x = a; r.y = b; return r; }

__device__ __forceinline__ float fast_cos(float x_rev) {
    return __builtin_amdgcn_cosf(__builtin_amdgcn_fractf(x_rev));
}

// packed atan2 for y >= 0 (y shared by both elements); result in [0, pi]
__device__ __forceinline__ v2f atan2_pos_pk(float yv, v2f x) {
    float ax0 = __builtin_fabsf(x.x), ax1 = __builtin_fabsf(x.y);
    float mn0 = fminf(ax0, yv), mx0 = fmaxf(ax0, yv);
    float mn1 = fminf(ax1, yv), mx1 = fmaxf(ax1, yv);
    v2f a = v2(mn0 * __builtin_amdgcn_rcpf(mx0), mn1 * __builtin_amdgcn_rcpf(mx1));
    v2f t = a * a;
    v2f p = ((((( -0.0117212f * t + 0.05265332f) * t - 0.11643287f) * t
              + 0.19354346f) * t - 0.33262347f) * t + 0.99997726f) * a;
    float p0 = (yv > ax0) ? (1.57079632679f - p.x) : p.x;
    float p1 = (yv > ax1) ? (1.57079632679f - p.y) : p.y;
    p0 = (x.x < 0.0f) ? (3.14159265359f - p0) : p0;
    p1 = (x.y < 0.0f) ? (3.14159265359f - p1) : p1;
    return v2(p0, p1);
}

// mirror-pair Phi11 (k3 = -g, +g); a/b sides packed as float2 lanes.
__device__ __forceinline__ float phi_pair_pk(float k1, float k1sq, float n2k1, float Ttk1,
                                             float L2, float s, float sqs, float k2sc, float g) {
    const float kk  = g * g + s;
    const float bk1 = Ttk1 * __builtin_amdgcn_exp2f((-1.0f/3.0f) * __builtin_amdgcn_logf(L2 * kk));
    const float Qh  = bk1 * g;
    const float sg  = 2.0f * s - kk;                    // s - g^2
    const float cc  = (bk1 * k1) * __builtin_amdgcn_rcpf(kk * s);
    const float yv  = bk1 * sqs;
    const float R   = bk1 * bk1 + kk;                   // s + bk1^2 + g^2
    const v2f x   = v2(kk - Qh, kk + Qh);
    const v2f C1  = cc * v2(sg + Qh, sg - Qh);
    const v2f kk0 = v2(R - 2.0f * Qh, R + 2.0f * Qh);
    const v2f th  = atan2_pos_pk(yv, x);
    const v2f vv  = L2 * kk0 + 1.0f;                    // 1 + u
    const v2f p   = v2(__builtin_amdgcn_exp2f((-17.0f/6.0f) * __builtin_amdgcn_logf(vv.x)),
                       __builtin_amdgcn_exp2f((-17.0f/6.0f) * __builtin_amdgcn_logf(vv.y)));
    const v2f z   = C1 - k2sc * (kk0 * th);
    const v2f k30 = v2(bk1 - g, bk1 + g);
    const v2f qq  = (s * z + n2k1 * k30) * z + (kk0 - k1sq);
    const v2f r   = p * qq;
    return r.x + r.y;
}

// far-field (beta->0) pair: mirror-sum cancels first-order beta; valid when max(ii,jj) >= FT
__device__ __forceinline__ float phi_pair_cheap(float k1sq, float L2, float s, float g) {
    const float kk = g * g + s;
    const float p  = __builtin_amdgcn_exp2f((-17.0f/6.0f) *
                     __builtin_amdgcn_logf(fmaf(L2, kk, 1.0f)));
    return 2.0f * p * (kk - k1sq);
}

__global__ __launch_bounds__(BLOCK, 2)
void spectral_kernel(const float* __restrict__ k1_in,
                     const float* __restrict__ dy_in,
                     const float* __restrict__ dz_in,
                     const float* __restrict__ plogL,
                     const float* __restrict__ plogT,
                     const float* __restrict__ plogM,
                     float* __restrict__ out)
{
    // phiT: single buffer per a: [a][32*SP]
    __shared__ __attribute__((aligned(16))) _Float16 s_phiT[2 * 32 * SP];
    __shared__ __attribute__((aligned(16))) _Float16 s_B3T[64 * SP];      // B1: [z][jj]
    __shared__ __attribute__((aligned(16))) _Float16 s_A2[64 * SA];       // A2: [y][ii]
    __shared__ float  s_grid[204];
    __shared__ float2 s_gw[204];     // {grid[j], trapz_w[j]}
    __shared__ float  s_dy[64], s_dz[64];
    __shared__ float  s_redA[8], s_redB[8], s_rden[2];

    const int t    = threadIdx.x;
    const int a0   = blockIdx.x * 2;
    const int lane = t & 63;
    const int w    = t >> 6;       // wave id 0..7: ia = w>>2, z-block = w&3
    const int n16  = lane & 15;
    const int quad = lane >> 4;

    const float L  = expf(plogL[0]);
    const float Tt = expf(plogT[0]);
    const float M  = expf(plogM[0]);
    const float L2 = L * L;
    const float L4 = L2 * L2;
    const float k1A   = k1_in[a0];
    const float k1B   = k1_in[a0 + 1];
    const float k1sqA = k1A * k1A,  k1sqB = k1B * k1B;
    const float n2k1A = -2.0f * k1A, n2k1B = -2.0f * k1B;
    const float Ttk1A = Tt * k1A,    Ttk1B = Tt * k1B;
    const float rk1A  = __builtin_amdgcn_rcpf(k1A);
    const float rk1B  = __builtin_amdgcn_rcpf(k1B);
    const float cM0   = (M * 0.25f / PI_F) * PW_SCALE * L4;   // a-independent

    // ---- grid ----
    if (t < 204) {
        int tt = min(t, 200);
        float v;
        if (tt < 100)       v = -exp2f(LOG2_10 * (-4.0f + 8.0f * (float)(99 - tt) * (1.0f/99.0f)));
        else if (tt == 100) v = 0.0f;
        else                v =  exp2f(LOG2_10 * (-4.0f + 8.0f * (float)(tt - 101) * (1.0f/99.0f)));
        s_grid[t] = v;
    }
    if (t < 64) { s_dy[t] = dy_in[t]; s_dz[t] = dz_in[t]; }
    __syncthreads();

    // ---- trapz weights packed with grid ----
    if (t < 204) {
        float wv = 0.0f;
        if (t == 0)          wv = 0.5f * (s_grid[1] - s_grid[0]);
        else if (t < 200)    wv = 0.5f * (s_grid[t+1] - s_grid[t-1]);
        else if (t == 200)   wv = 0.5f * (s_grid[200] - s_grid[199]);
        s_gw[t] = make_float2(s_grid[t], wv);
    }
    // ---- B3T[z][jj] = cos(grid[100+jj]*dz[z]) f16, jj < 96 (rolled) ----
    {
        const int jjp = lane;
        const int jj0 = 2 * jjp, jj1 = jj0 + 1;
        if (jj0 < 96) {
            const float g0 = s_grid[100 + jj0];
            const float g1 = s_grid[100 + jj1];
            const int jjg  = jjp >> 2;
            #pragma unroll 1
            for (int m = 0; m < 8; ++m) {
                int z = w + 8 * m;
                float dzr = s_dz[z] * INV2PI;
                float c0 = (jj0 < 88) ? fast_cos(g0 * dzr) : 0.0f;
                float c1 = (jj1 < 88) ? fast_cos(g1 * dzr) : 0.0f;
                half2v pr; pr.x = (_Float16)c0; pr.y = (_Float16)c1;
                *(half2v*)&s_B3T[z * SP + ((jjg ^ (z & 7)) << 3) + (jj0 & 7)] = pr;
            }
        }
    }
    // ---- A2[y][ii] = cos(grid2[ii]*dy[y]) f16, ii < 96 (rolled) ----
    {
        float dyr = s_dy[lane] * INV2PI;
        #pragma unroll 1
        for (int k = 0; k < 6; ++k) {
            int iip = w + 8 * k;               // 0..47 -> ii 0..95
            int i0 = 2 * iip, i1 = i0 + 1;
            float c0 = (i0 < 88) ? fast_cos(s_grid[100 + i0] * dyr) : 0.0f;
            float c1 = (i1 < 88) ? fast_cos(s_grid[100 + i1] * dyr) : 0.0f;
            half2v pr; pr.x = (_Float16)c0; pr.y = (_Float16)c1;
            int off = lane * SA + (((iip >> 2) ^ (lane & 7)) << 3) + ((iip & 3) << 1);
            *(half2v*)&s_A2[off] = pr;
        }
    }
    __syncthreads();

    float f1A = 0.0f, f1B = 0.0f;
    f32x4 acc2[4];
    #pragma unroll
    for (int i = 0; i < 4; ++i) acc2[i] = (f32x4){0.f, 0.f, 0.f, 0.f};

    _Float16* pA = s_phiT;              // a0 phi tile
    _Float16* pB = s_phiT + 32 * SP;    // a1 phi tile
    const int ia = w >> 2;              // wave's a-index
    const int zb = w & 3;               // wave's z-block

    for (int c = 0; c < 3; ++c) {
        // chunk parameters: Rf = full rows, R = produced rows (rest zero), iiB = base
        const int Rf  = (c == 0) ? 32 : ((c == 1) ? 24 : 0);
        const int R   = (c == 2) ? 24 : 32;
        const int iiB = c * 32;

        // ---- zeros: granule 11 every chunk; rows 24..31 all granules when c==2 ----
        if (t < 32) {
            half8 zz = {};
            int off = t * SP + ((11 ^ (t & 7)) << 3);
            *(half8*)&pA[off] = zz;
            *(half8*)&pB[off] = zz;
        }
        if (c == 2 && t < 96) {
            int row = 24 + t / 12, g = t - (row - 24) * 12;
            half8 zz = {};
            int off = row * SP + ((g ^ (row & 7)) << 3);
            *(half8*)&pA[off] = zz;
            *(half8*)&pB[off] = zz;
        }

        // ---- full cells: rows 0..Rf-1 x jj 0..55 (rolled) ----
        const int Nf = Rf * FT;
        #pragma unroll 1
        for (int e = t; e < Nf; e += BLOCK) {
            int row = e / FT, jj = e - row * FT;
            int ii  = iiB + row;
            float k2  = s_gw[100 + ii].x;
            float cMw = cM0 * (s_gw[100 + ii].y * ((ii == 0) ? 1.0f : 2.0f));
            float2 gwv = s_gw[100 + jj];
            float cw  = cMw * ((jj == 0) ? 0.5f * gwv.y : gwv.y);
            float sA   = k1sqA + k2 * k2;
            float rsA  = __builtin_amdgcn_rsqf(sA);
            float valA = phi_pair_pk(k1A, k1sqA, n2k1A, Ttk1A, L2, sA, sA * rsA,
                                     (k2 * rk1A) * k2 * (rsA * rsA * rsA), gwv.x) * cw;
            float sB   = k1sqB + k2 * k2;
            float rsB  = __builtin_amdgcn_rsqf(sB);
            float valB = phi_pair_pk(k1B, k1sqB, n2k1B, Ttk1B, L2, sB, sB * rsB,
                                     (k2 * rk1B) * k2 * (rsB * rsB * rsB), gwv.x) * cw;
            f1A += valA; f1B += valB;
            int off = row * SP + (((jj >> 3) ^ (row & 7)) << 3) + (jj & 7);
            pA[off] = (_Float16)valA;
            pB[off] = (_Float16)valB;
        }
        // ---- cheap part 1: rows 0..R-1 x jj 56..87 (rolled) ----
        const int N1 = R * 32;
        #pragma unroll 1
        for (int e = t; e < N1; e += BLOCK) {
            int row = e >> 5, jj = FT + (e & 31);
            int ii  = iiB + row;
            float k2  = s_gw[100 + ii].x;
            float cMw = cM0 * (s_gw[100 + ii].y * ((ii == 0) ? 1.0f : 2.0f));
            float2 gwv = s_gw[100 + jj];
            float cw  = cMw * gwv.y;                       // jj >= 56, never 0
            float valA = phi_pair_cheap(k1sqA, L2, k1sqA + k2 * k2, gwv.x) * cw;
            float valB = phi_pair_cheap(k1sqB, L2, k1sqB + k2 * k2, gwv.x) * cw;
            f1A += valA; f1B += valB;
            int off = row * SP + (((jj >> 3) ^ (row & 7)) << 3) + (jj & 7);
            pA[off] = (_Float16)valA;
            pB[off] = (_Float16)valB;
        }
        // ---- cheap part 2: rows Rf..R-1 x jj 0..55 (rolled) ----
        const int N2 = (R - Rf) * FT;
        #pragma unroll 1
        for (int e = t; e < N2; e += BLOCK) {
            int r2 = e / FT, jj = e - r2 * FT;
            int row = Rf + r2;
            int ii  = iiB + row;
            float k2  = s_gw[100 + ii].x;
            float cMw = cM0 * (s_gw[100 + ii].y * 2.0f);   // ii >= 24 here, never 0
            float2 gwv = s_gw[100 + jj];
            float cw  = cMw * ((jj == 0) ? 0.5f * gwv.y : gwv.y);
            float valA = phi_pair_cheap(k1sqA, L2, k1sqA + k2 * k2, gwv.x) * cw;
            float valB = phi_pair_cheap(k1sqB, L2, k1sqB + k2 * k2, gwv.x) * cw;
            f1A += valA; f1B += valB;
            int off = row * SP + (((jj >> 3) ^ (row & 7)) << 3) + (jj & 7);
            pA[off] = (_Float16)valA;
            pB[off] = (_Float16)valB;
        }
        __syncthreads();   // phiT ready

        // ---- stage 1 (MFMA, wave-local): TcT[ii 0..31][z-block zb], K=96 ----
        const _Float16* rp = s_phiT + ia * (32 * SP);
        f32x4 acc1[2];
        acc1[0] = (f32x4){0.f,0.f,0.f,0.f};
        acc1[1] = (f32x4){0.f,0.f,0.f,0.f};
        {
            const int arow0 = n16;
            const int arow1 = 16 + n16;
            const int brow  = zb * 16 + n16;
            #pragma unroll
            for (int ks = 0; ks < 3; ++ks) {
                int kg = ks * 4 + quad;
                half8 af0 = *(const half8*)&rp[arow0 * SP + ((kg ^ (arow0 & 7)) << 3)];
                half8 af1 = *(const half8*)&rp[arow1 * SP + ((kg ^ (arow1 & 7)) << 3)];
                half8 bf  = *(const half8*)&s_B3T[brow * SP + ((kg ^ (brow & 7)) << 3)];
                acc1[0] = __builtin_amdgcn_mfma_f32_16x16x32_f16(af0, bf, acc1[0], 0, 0, 0);
                acc1[1] = __builtin_amdgcn_mfma_f32_16x16x32_f16(af1, bf, acc1[1], 0, 0, 0);
            }
        }

        // ---- in-wave C->B transpose: bf2[j] = TcT[ii=quad*8+j][z=zb*16+n16] ----
        half8 bf2;
        {
            half2v hA0; hA0.x = (_Float16)acc1[0].x; hA0.y = (_Float16)acc1[0].y;
            half2v hA1; hA1.x = (_Float16)acc1[0].z; hA1.y = (_Float16)acc1[0].w;
            half2v hB0; hB0.x = (_Float16)acc1[1].x; hB0.y = (_Float16)acc1[1].y;
            half2v hB1; hB1.x = (_Float16)acc1[1].z; hB1.y = (_Float16)acc1[1].w;
            int pkA0 = __builtin_bit_cast(int, hA0);
            int pkA1 = __builtin_bit_cast(int, hA1);
            int pkB0 = __builtin_bit_cast(int, hB0);
            int pkB1 = __builtin_bit_cast(int, hB1);
            const int addr_a = (((quad & 1) << 5) + n16) << 2;
            const int addr_b = addr_a + 64;
            int a0v = __builtin_amdgcn_ds_bpermute(addr_a, pkA0);
            int b0v = __builtin_amdgcn_ds_bpermute(addr_a, pkB0);
            int a1v = __builtin_amdgcn_ds_bpermute(addr_a, pkA1);
            int b1v = __builtin_amdgcn_ds_bpermute(addr_a, pkB1);
            int a2v = __builtin_amdgcn_ds_bpermute(addr_b, pkA0);
            int b2v = __builtin_amdgcn_ds_bpermute(addr_b, pkB0);
            int a3v = __builtin_amdgcn_ds_bpermute(addr_b, pkA1);
            int b3v = __builtin_amdgcn_ds_bpermute(addr_b, pkB1);
            const bool lo = (quad < 2);
            i32x4 wv;
            wv.x = lo ? a0v : b0v;
            wv.y = lo ? a1v : b1v;
            wv.z = lo ? a2v : b2v;
            wv.w = lo ? a3v : b3v;
            bf2 = __builtin_bit_cast(half8, wv);
        }

        // ---- stage 2 (MFMA): out[y-blocks][z-block zb] += A2 * bf2, K=32 ----
        {
            const int G = c * 4 + quad;
            #pragma unroll
            for (int yb = 0; yb < 4; ++yb) {
                int yrow = yb * 16 + n16;
                half8 a2f = *(const half8*)&s_A2[yrow * SA + ((G ^ (yrow & 7)) << 3)];
                acc2[yb] = __builtin_amdgcn_mfma_f32_16x16x32_f16(a2f, bf2, acc2[yb], 0, 0, 0);
            }
        }
        __syncthreads();   // phiT overwritten next chunk
    }

    // ---- F1 reductions -> 1/|F1| per a ----
    float vA = f1A, vB = f1B;
    #pragma unroll
    for (int off = 32; off > 0; off >>= 1) {
        vA += __shfl_down(vA, off, 64);
        vB += __shfl_down(vB, off, 64);
    }
    if (lane == 0) { s_redA[w] = vA; s_redB[w] = vB; }
    __syncthreads();
    if (t == 0) {
        float sA = 0.0f, sB = 0.0f;
        #pragma unroll
        for (int i = 0; i < 8; ++i) { sA += s_redA[i]; sB += s_redB[i]; }
        s_rden[0] = 1.0f / fabsf(sA);
        s_rden[1] = 1.0f / fabsf(sB);
    }
    __syncthreads();
    const float rden = s_rden[ia];

    // ---- epilogue: acc2[yb][r] = out[a0+ia][y = yb*16+quad*4+r][z = zb*16+n16] ----
    float* op = out + ((size_t)(a0 + ia) << 12) + (zb * 16 + n16);
    #pragma unroll
    for (int yb = 0; yb < 4; ++yb) {
        #pragma unroll
        for (int r = 0; r < 4; ++r) {
            int y = yb * 16 + quad * 4 + r;
            op[y * 64] = acc2[yb][r] * rden;
        }
    }
}

extern "C" void kernel_launch(void* const* d_in, const int* in_sizes, int n_in,
                              void* d_out, int out_size, void* d_ws, size_t ws_size,
                              hipStream_t stream) {
    const float* k1 = (const float*)d_in[0];
    const float* dy = (const float*)d_in[1];
    const float* dz = (const float*)d_in[2];
    const float* lL = (const float*)d_in[3];
    const float* lT = (const float*)d_in[4];
    const float* lM = (const float*)d_in[5];
    float* outp = (float*)d_out;
    hipLaunchKernelGGL(spectral_kernel, dim3(256), dim3(BLOCK), 0, stream,
                       k1, dy, dz, lL, lT, lM, outp);
}